// Round 7
// baseline (139.194 us; speedup 1.0000x reference)
//
#include <hip/hip_runtime.h>

// GraphSAGE fused layer: out[B,128] = relu(concat(feat[nodes], mean_s feat[neigh])[B,256] @ W[256,128])
// B=50000, S=10, D=128, H=128. fp32 in/out; bf16 MFMA (threshold allows bf16).
//
// R7: attack per-thread memory-level parallelism. R6 post-mortem: gather is
// latency-bound with VGPR=36 -> compiler batches the 22 loads/thread into ~4
// dependent groups. Now: 32 threads/row, 16 rows/block -> 11 independent 16B
// loads/thread, explicitly staged into v[10] before any accumulation, under
// an 85-VGPR cap (LB(512,6), 3 blocks/CU = 75% occupancy). One waitcnt shadow
// covers every byte a thread will ever gather.

typedef __attribute__((ext_vector_type(8))) short bf16x8;   // 8 bf16 (4 VGPRs)
typedef __attribute__((ext_vector_type(4))) float f32x4;    // MFMA C/D frag

__device__ __forceinline__ unsigned short f2bf(float x) {
  unsigned int u = __float_as_uint(x);
  u += 0x7fffu + ((u >> 16) & 1u);
  return (unsigned short)(u >> 16);
}

// W [K=256][H=128] fp32 row-major -> Wt [H=128][K=256] bf16 (once, to ws).
__global__ void sage_prep_wt(const float* __restrict__ W,
                             unsigned short* __restrict__ Wt) {
  int tid = blockIdx.x * blockDim.x + threadIdx.x;   // 0..8191 (float4 units)
  float4 v = ((const float4*)W)[tid];
  int flat = tid << 2;
  int k = flat >> 7;          // / H
  int h = flat & 127;         // % H
  Wt[(h + 0) * 256 + k] = f2bf(v.x);
  Wt[(h + 1) * 256 + k] = f2bf(v.y);
  Wt[(h + 2) * 256 + k] = f2bf(v.z);
  Wt[(h + 3) * 256 + k] = f2bf(v.w);
}

__global__ __launch_bounds__(512, 6)
void sage_fused4(const int* __restrict__ nodes,
                 const int* __restrict__ neigh,
                 const float* __restrict__ feat,
                 const unsigned short* __restrict__ Wt,
                 float* __restrict__ out, int B)
{
  constexpr int K = 256, H = 128, S = 10;
  constexpr int TILE = 16;
  constexpr int STR = K + 8;                   // 264 elems = 528 B rows (bank shift 4)
  __shared__ unsigned short Clds[TILE * STR];  // 8.4 KB

  const int t = threadIdx.x;
  const int block0 = blockIdx.x * TILE;

  // ---- Phase 1: gather self + mean(neigh) -> LDS tile (bf16) ----
  {
    const int r   = t >> 5;     // 0..15
    const int sub = t & 31;     // 32 threads/row; thread covers elems 4sub..4sub+3
    const int b   = block0 + r;
    unsigned short* crow = &Clds[r * STR];
    if (b < B) {
      const float4* f4 = (const float4*)feat;   // feature row = 32 float4

      // 10 independent index loads first.
      int nidx[S];
#pragma unroll
      for (int s = 0; s < S; ++s) nidx[s] = neigh[b * S + s];
      const long srow = (long)nodes[b] * 32;

      // 11 independent feature loads, all in flight before any use.
      float4 self = f4[srow + sub];
      float4 v[S];
#pragma unroll
      for (int s = 0; s < S; ++s) v[s] = f4[(long)nidx[s] * 32 + sub];

      float ax = 0.f, ay = 0.f, az = 0.f, aw = 0.f;
#pragma unroll
      for (int s = 0; s < S; ++s) { ax += v[s].x; ay += v[s].y; az += v[s].z; aw += v[s].w; }

      ushort4 o;
      o.x = f2bf(self.x); o.y = f2bf(self.y); o.z = f2bf(self.z); o.w = f2bf(self.w);
      *(ushort4*)&crow[4 * sub] = o;                       // self half [0,128)
      o.x = f2bf(ax * 0.1f); o.y = f2bf(ay * 0.1f);
      o.z = f2bf(az * 0.1f); o.w = f2bf(aw * 0.1f);
      *(ushort4*)&crow[128 + 4 * sub] = o;                 // mean half [128,256)
    } else {
      ushort4 z; z.x = z.y = z.z = z.w = 0;
      *(ushort4*)&crow[4 * sub] = z;
      *(ushort4*)&crow[128 + 4 * sub] = z;
    }
  }
  __syncthreads();
  __builtin_amdgcn_sched_barrier(0);   // keep Wt loads out of phase-1 lifetime

  // ---- Phase 2: 8 waves x one 16x16 tile (cols wave*16..+15) ----
  const int lane = t & 63;
  const int wave = t >> 6;
  const int m    = lane & 15;
  const int quad = lane >> 4;
  const int cbase = wave * 16;      // 8 waves x 16 = 128 cols

  bf16x8 bfrag[8];
#pragma unroll
  for (int ks = 0; ks < 8; ++ks)
    bfrag[ks] = *(const bf16x8*)&Wt[(cbase + m) * K + ks * 32 + quad * 8];

  f32x4 acc = {0.f, 0.f, 0.f, 0.f};
#pragma unroll
  for (int ks = 0; ks < 8; ++ks) {
    bf16x8 a = *(const bf16x8*)&Clds[m * STR + ks * 32 + quad * 8];
    acc = __builtin_amdgcn_mfma_f32_16x16x32_bf16(a, bfrag[ks], acc, 0, 0, 0);
  }

  // C/D layout: col = lane&15, row = quad*4 + reg (verified m89/m91)
#pragma unroll
  for (int reg = 0; reg < 4; ++reg) {
    const int gb = block0 + quad * 4 + reg;
    if (gb < B) out[(size_t)gb * H + cbase + m] = fmaxf(acc[reg], 0.0f);
  }
}

extern "C" void kernel_launch(void* const* d_in, const int* in_sizes, int n_in,
                              void* d_out, int out_size, void* d_ws, size_t ws_size,
                              hipStream_t stream) {
  const int*   nodes = (const int*)d_in[0];
  const int*   neigh = (const int*)d_in[1];
  const float* feat  = (const float*)d_in[2];
  const float* W     = (const float*)d_in[3];
  float*       out   = (float*)d_out;
  const int B = in_sizes[0];                       // 50000

  unsigned short* Wt = (unsigned short*)d_ws;      // 64 KB
  sage_prep_wt<<<32, 256, 0, stream>>>(W, Wt);
  const int grid = (B + 15) / 16;                  // 3125
  sage_fused4<<<grid, 512, 0, stream>>>(nodes, neigh, feat, Wt, out, B);
}